// Round 1
// baseline (80.734 us; speedup 1.0000x reference)
//
#include <hip/hip_runtime.h>
#include <math.h>

#define D  16    // latent_dim
#define JT 256   // j columns per block == blockDim.x
#define TI 32    // i rows per block

__global__ __launch_bounds__(256) void MLPDecoder_68092411511098_kernel(
    const float* __restrict__ z, const float* __restrict__ W1,
    const float* __restrict__ b1, const float* __restrict__ W2,
    const float* __restrict__ b2, float* __restrict__ out, int N)
{
    __shared__ float sW1[2 * D * D];  // 512 floats: W1 (32x16) row-major
    __shared__ float sZi[TI * D];     // 512 floats: z rows for this i-tile
    __shared__ float sGi[TI * D];     // 512 floats: hi tile (no b1)

    const int tid   = threadIdx.x;
    const int jbase = blockIdx.x * JT;
    const int ibase = blockIdx.y * TI;

    // ---- stage W1 and the z i-tile into LDS ----
    sW1[tid]       = W1[tid];
    sW1[tid + 256] = W1[tid + 256];
    if (tid < (TI * D) / 4) {
        ((float4*)sZi)[tid] = ((const float4*)(z + (size_t)ibase * D))[tid];
    }
    __syncthreads();

    // ---- per-thread g_j for j = jbase + tid (b1 folded in) ----
    float zr[D];
    {
        const float4* zrow = (const float4*)(z + (size_t)(jbase + tid) * D);
        float4 a = zrow[0], b = zrow[1], c = zrow[2], e = zrow[3];
        zr[0]=a.x;  zr[1]=a.y;  zr[2]=a.z;  zr[3]=a.w;
        zr[4]=b.x;  zr[5]=b.y;  zr[6]=b.z;  zr[7]=b.w;
        zr[8]=c.x;  zr[9]=c.y;  zr[10]=c.z; zr[11]=c.w;
        zr[12]=e.x; zr[13]=e.y; zr[14]=e.z; zr[15]=e.w;
    }
    float gj[D];
    #pragma unroll
    for (int k = 0; k < D; ++k) {
        float acc = b1[k];                       // uniform -> scalar load
        #pragma unroll
        for (int m = 0; m < D; ++m)
            acc = fmaf(zr[m], sW1[(D + m) * D + k], acc);  // W1_j = W1[16:]
        gj[k] = acc;
    }

    // ---- cooperative g_i tile: TI*D = 512 values, 2 per thread ----
    #pragma unroll
    for (int v = tid; v < TI * D; v += 256) {
        const int ii = v >> 4, k = v & (D - 1);
        float acc = 0.0f;
        #pragma unroll
        for (int m = 0; m < D; ++m)
            acc = fmaf(sZi[ii * D + m], sW1[m * D + k], acc); // W1_i = W1[:16]
        sGi[v] = acc;
    }

    // ---- uniform small weights into registers ----
    float w2r[D];
    #pragma unroll
    for (int k = 0; k < D; ++k) w2r[k] = W2[k];  // uniform -> scalar loads
    const float b2s = b2[0];
    __syncthreads();

    // ---- main pairwise loop: one output column per thread, TI rows ----
    float* orow = out + (size_t)ibase * N + jbase + tid;
    for (int ii = 0; ii < TI; ++ii) {
        const float4* g4 = (const float4*)(sGi + ii * D);  // broadcast reads
        float4 g0 = g4[0], g1 = g4[1], g2 = g4[2], g3 = g4[3];
        float gi[D] = {g0.x,g0.y,g0.z,g0.w, g1.x,g1.y,g1.z,g1.w,
                       g2.x,g2.y,g2.z,g2.w, g3.x,g3.y,g3.z,g3.w};
        float acc = b2s;
        #pragma unroll
        for (int k = 0; k < D; ++k) {
            float t = gi[k] + gj[k];
            acc = fmaf(fmaxf(t, 0.0f), w2r[k], acc);
        }
        const float e = __expf(-acc);
        orow[(size_t)ii * N] = __builtin_amdgcn_rcpf(1.0f + e);
    }
}

extern "C" void kernel_launch(void* const* d_in, const int* in_sizes, int n_in,
                              void* d_out, int out_size, void* d_ws, size_t ws_size,
                              hipStream_t stream) {
    const float* z  = (const float*)d_in[0];
    const float* W1 = (const float*)d_in[1];
    const float* b1 = (const float*)d_in[2];
    const float* W2 = (const float*)d_in[3];
    const float* b2 = (const float*)d_in[4];
    float* out = (float*)d_out;

    const int N = in_sizes[0] / D;   // 2048
    dim3 grid(N / JT, N / TI);       // (8, 64) = 512 blocks
    MLPDecoder_68092411511098_kernel<<<grid, dim3(256), 0, stream>>>(
        z, W1, b1, W2, b2, out, N);
}

// Round 2
// 73.362 us; speedup vs baseline: 1.1005x; 1.1005x over previous
//
#include <hip/hip_runtime.h>
#include <math.h>

#define D  16     // latent_dim
#define JT 256    // j columns per block == blockDim.x
#define TI 8      // i rows per block

typedef _Float16 half2v __attribute__((ext_vector_type(2)));
union H2U { half2v h; unsigned int u; };

// ---------- prep: Hi[i][k] = z[i]@W1[:16][:,k] + b1[k], Hj[j][k] = z[j]@W1[16:][:,k]
// packed as 8 half2 (k-pairs) per row; also packs W2 into 8 half2.
__global__ __launch_bounds__(256) void prep_kernel(
    const float* __restrict__ z, const float* __restrict__ W1,
    const float* __restrict__ b1, const float* __restrict__ W2,
    half2v* __restrict__ Hi, half2v* __restrict__ Hj, half2v* __restrict__ w2p)
{
    __shared__ float sZ[16 * D];   // 16 rows of z
    __shared__ float sW[2 * D * D];
    const int tid = threadIdx.x;
    const int rowbase = blockIdx.x * 16;
    if (tid < 64)       ((float4*)sZ)[tid]      = ((const float4*)(z + (size_t)rowbase * D))[tid];
    else if (tid < 192) ((float4*)sW)[tid - 64] = ((const float4*)W1)[tid - 64];
    __syncthreads();

    const int r  = tid >> 4;      // local row 0..15
    const int u  = tid & 15;
    const int hf = u >> 3;        // 0 = i-half, 1 = j-half
    const int p  = u & 7;         // k-pair 0..7
    const int k0 = 2 * p, k1 = k0 + 1;

    float a0 = 0.f, a1 = 0.f;
    #pragma unroll
    for (int m = 0; m < D; ++m) {
        const float zf = sZ[r * D + m];
        const float* wrow = &sW[(hf * D + m) * D];
        a0 = fmaf(zf, wrow[k0], a0);
        a1 = fmaf(zf, wrow[k1], a1);
    }
    if (hf == 0) { a0 += b1[k0]; a1 += b1[k1]; }   // fold b1 into i-side

    H2U hv; hv.h.x = (_Float16)a0; hv.h.y = (_Float16)a1;
    (hf ? Hj : Hi)[(size_t)(rowbase + r) * 8 + p] = hv.h;

    if (blockIdx.x == 0 && tid < 8) {
        H2U wv; wv.h.x = (_Float16)W2[2 * tid]; wv.h.y = (_Float16)W2[2 * tid + 1];
        w2p[tid] = wv.h;
    }
}

// ---------- main pairwise kernel
__global__ __launch_bounds__(256) void MLPDecoder_68092411511098_kernel(
    const half2v* __restrict__ Hi, const half2v* __restrict__ Hj,
    const half2v* __restrict__ w2p, const float* __restrict__ b2,
    float* __restrict__ out, int N)
{
    __shared__ half2v sHi[TI * 8];
    const int tid   = threadIdx.x;
    const int jbase = blockIdx.x * JT;
    const int ibase = blockIdx.y * TI;

    if (tid < TI * 8) sHi[tid] = Hi[(size_t)ibase * 8 + tid];  // coalesced dwords

    // per-thread j fragment: 8 half2 (32 B) via two dwordx4 loads
    half2v vj[8];
    {
        const uint4* src = (const uint4*)(Hj + (size_t)(jbase + tid) * 8);
        union { uint4 q; half2v h[4]; } c0, c1;
        c0.q = src[0]; c1.q = src[1];
        vj[0]=c0.h[0]; vj[1]=c0.h[1]; vj[2]=c0.h[2]; vj[3]=c0.h[3];
        vj[4]=c1.h[0]; vj[5]=c1.h[1]; vj[6]=c1.h[2]; vj[7]=c1.h[3];
    }
    half2v w2v[8];
    #pragma unroll
    for (int p = 0; p < 8; ++p) w2v[p] = w2p[p];   // uniform -> scalar loads
    const float b2s = b2[0];
    const half2v zero = {(_Float16)0.f, (_Float16)0.f};
    __syncthreads();

    float* orow = out + (size_t)ibase * N + jbase + tid;
    #pragma unroll 2
    for (int ii = 0; ii < TI; ++ii) {
        const half2v* hrow = &sHi[ii * 8];         // broadcast ds_read_b128 x2
        float acc = b2s;
        #pragma unroll
        for (int p = 0; p < 8; ++p) {
            half2v s = hrow[p] + vj[p];                        // v_pk_add_f16
            half2v r = __builtin_elementwise_max(s, zero);     // v_pk_max_f16
#if __has_builtin(__builtin_amdgcn_fdot2)
            acc = __builtin_amdgcn_fdot2(r, w2v[p], acc, false); // v_dot2_f32_f16
#else
            acc += (float)r.x * (float)w2v[p].x + (float)r.y * (float)w2v[p].y;
#endif
        }
        const float e = __expf(-acc);
        orow[(size_t)ii * N] = __builtin_amdgcn_rcpf(1.0f + e);
    }
}

extern "C" void kernel_launch(void* const* d_in, const int* in_sizes, int n_in,
                              void* d_out, int out_size, void* d_ws, size_t ws_size,
                              hipStream_t stream) {
    const float* z  = (const float*)d_in[0];
    const float* W1 = (const float*)d_in[1];
    const float* b1 = (const float*)d_in[2];
    const float* W2 = (const float*)d_in[3];
    const float* b2 = (const float*)d_in[4];
    float* out = (float*)d_out;

    const int N = in_sizes[0] / D;         // 2048

    half2v* Hi  = (half2v*)d_ws;           // N*8 half2 = N*32 B
    half2v* Hj  = Hi + (size_t)N * 8;
    half2v* w2p = Hj + (size_t)N * 8;

    prep_kernel<<<dim3(N / 16), dim3(256), 0, stream>>>(z, W1, b1, W2, Hi, Hj, w2p);

    dim3 grid(N / JT, N / TI);             // (8, 256) = 2048 blocks
    MLPDecoder_68092411511098_kernel<<<grid, dim3(256), 0, stream>>>(
        Hi, Hj, w2p, b2, out, N);
}